// Round 1
// 306.355 us; speedup vs baseline: 1.0875x; 1.0875x over previous
//
#include <hip/hip_runtime.h>
#include <hip/hip_bf16.h>

typedef __bf16 bf16_t;
typedef __attribute__((ext_vector_type(8))) __bf16 bf16x8;
typedef __attribute__((ext_vector_type(4))) float f32x4;

#define BH 64
#define KP 512
#define NN 4096
#define DD 64
#define GSZ (BH * KP * DD)  // offset of gV in d_out

#define MFMA16(a, b, c) __builtin_amdgcn_mfma_f32_16x16x32_bf16((a), (b), (c), 0, 0, 0)

__device__ __forceinline__ bf16x8 cvt8v(const f32x4 lo, const f32x4 hi) {
  bf16x8 r;
  r[0] = (bf16_t)lo[0]; r[1] = (bf16_t)lo[1]; r[2] = (bf16_t)lo[2]; r[3] = (bf16_t)lo[3];
  r[4] = (bf16_t)hi[0]; r[5] = (bf16_t)hi[1]; r[6] = (bf16_t)hi[2]; r[7] = (bf16_t)hi[3];
  return r;
}
__device__ __forceinline__ bf16x8 cvt8(const float* __restrict__ p) {
  return cvt8v(*(const f32x4*)p, *(const f32x4*)(p + 4));
}

// global->LDS DMA, 16B per lane; lds dest is wave-uniform base + lane*16.
__device__ __forceinline__ void stage16(bf16_t* lds_base, const bf16_t* gsrc) {
  __builtin_amdgcn_global_load_lds(
      (const __attribute__((address_space(1))) void*)gsrc,
      (__attribute__((address_space(3))) void*)lds_base, 16, 0, 0);
}

// ---------------------------------------------------------------------------
// Prep: bf16 conversion + global transposes.
//   xk16 [bh][n][d]  (natural bf16)
//   xkT16[bh][d][n], xvT16[bh][d][n]  (transposed bf16)
// Grid (NN/64, BH) x 256. Pure BW kernel (~225 MB traffic).
// ---------------------------------------------------------------------------
__global__ __launch_bounds__(256) void hop_prep(
    const float* __restrict__ xk, const float* __restrict__ xv,
    bf16_t* __restrict__ xk16, bf16_t* __restrict__ xkT16, bf16_t* __restrict__ xvT16)
{
  __shared__ __align__(16) bf16_t T[64 * 72];
  const int t = threadIdx.x;
  const int n0 = blockIdx.x * 64;
  const int bh = blockIdx.y;
  const int row = t >> 2;          // in-tile n (load phase)
  const int d0  = (t & 3) * 16;
  const int dcol = t >> 2;         // in-tile d (transpose-read phase)
  const int nb   = (t & 3) * 16;
  const size_t gb  = (size_t)bh * NN * DD;
  const size_t gbT = (size_t)bh * DD * NN;

  // ---- xk: natural bf16 + transpose ----
  {
    const float* src = xk + gb + (size_t)(n0 + row) * DD + d0;
    const f32x4 a0 = *(const f32x4*)(src);
    const f32x4 a1 = *(const f32x4*)(src + 4);
    const f32x4 a2 = *(const f32x4*)(src + 8);
    const f32x4 a3 = *(const f32x4*)(src + 12);
    const bf16x8 lo = cvt8v(a0, a1), hi = cvt8v(a2, a3);
    bf16_t* dn = xk16 + gb + (size_t)(n0 + row) * DD + d0;
    *(bf16x8*)(dn)     = lo;
    *(bf16x8*)(dn + 8) = hi;
    *(bf16x8*)(T + row * 72 + d0)     = lo;
    *(bf16x8*)(T + row * 72 + d0 + 8) = hi;
  }
  __syncthreads();
  {
    bf16x8 o0, o1;
    #pragma unroll
    for (int j = 0; j < 8; j++) o0[j] = T[(nb + j) * 72 + dcol];
    #pragma unroll
    for (int j = 0; j < 8; j++) o1[j] = T[(nb + 8 + j) * 72 + dcol];
    bf16_t* dT = xkT16 + gbT + (size_t)dcol * NN + n0 + nb;
    *(bf16x8*)(dT)     = o0;
    *(bf16x8*)(dT + 8) = o1;
  }
  __syncthreads();
  // ---- xv: transpose only ----
  {
    const float* src = xv + gb + (size_t)(n0 + row) * DD + d0;
    const f32x4 a0 = *(const f32x4*)(src);
    const f32x4 a1 = *(const f32x4*)(src + 4);
    const f32x4 a2 = *(const f32x4*)(src + 8);
    const f32x4 a3 = *(const f32x4*)(src + 12);
    *(bf16x8*)(T + row * 72 + d0)     = cvt8v(a0, a1);
    *(bf16x8*)(T + row * 72 + d0 + 8) = cvt8v(a2, a3);
  }
  __syncthreads();
  {
    bf16x8 o0, o1;
    #pragma unroll
    for (int j = 0; j < 8; j++) o0[j] = T[(nb + j) * 72 + dcol];
    #pragma unroll
    for (int j = 0; j < 8; j++) o1[j] = T[(nb + 8 + j) * 72 + dcol];
    bf16_t* dT = xvT16 + gbT + (size_t)dcol * NN + n0 + nb;
    *(bf16x8*)(dT)     = o0;
    *(bf16x8*)(dT + 8) = o1;
  }
}

// ---------------------------------------------------------------------------
// Pass 1: inv_colsum[bh][n] = 1 / sum_k exp(K[k].xk[n]).
// 1-D grid 1024, XCD-bijective swizzle: blocks of same bh share an XCD's L2
// (K slab reuse). B-frags now straight bf16 loads from xk16 (no cvt).
// ---------------------------------------------------------------------------
__global__ __launch_bounds__(256) void hop_pass1(
    const float* __restrict__ Km, const bf16_t* __restrict__ xk16,
    float* __restrict__ inv_colsum)
{
  __shared__ __align__(16) bf16_t Ks[128 * 72];

  const int tid  = threadIdx.x;
  const int wave = tid >> 6, lane = tid & 63;
  const int col  = lane & 15, quad = lane >> 4;
  const int bid  = blockIdx.x;
  const int bh   = (bid & 7) + 8 * ((bid >> 3) & 7);  // same-bh blocks -> same XCD
  const int n0   = (bid >> 6) * 256 + wave * 64;

  const float*  Kb   = Km   + (size_t)bh * KP * DD;
  const bf16_t* xkb  = xk16 + (size_t)bh * NN * DD;

  bf16x8 bf[4][2];
  #pragma unroll
  for (int nsub = 0; nsub < 4; nsub++) {
    const bf16_t* p = xkb + (size_t)(n0 + nsub * 16 + col) * DD + quad * 8;
    bf[nsub][0] = *(const bf16x8*)(p);
    bf[nsub][1] = *(const bf16x8*)(p + 32);
  }

  float colacc[4] = {0.f, 0.f, 0.f, 0.f};
  const int srow = tid >> 1, sdo = (tid & 1) * 32;

  for (int kc = 0; kc < KP; kc += 128) {
    __syncthreads();
    const float* src = Kb + (size_t)(kc + srow) * DD + sdo;
    #pragma unroll
    for (int u = 0; u < 4; u++) {
      const f32x4 p0 = *(const f32x4*)(src + 8 * u);
      const f32x4 p1 = *(const f32x4*)(src + 8 * u + 4);
      *(bf16x8*)(Ks + srow * 72 + sdo + 8 * u) = cvt8v(p0, p1);
    }
    __syncthreads();
    #pragma unroll
    for (int ks = 0; ks < 8; ks++) {
      const bf16x8 a0 = *(const bf16x8*)(Ks + (ks * 16 + col) * 72 + quad * 8);
      const bf16x8 a1 = *(const bf16x8*)(Ks + (ks * 16 + col) * 72 + 32 + quad * 8);
      #pragma unroll
      for (int nsub = 0; nsub < 4; nsub++) {
        f32x4 c = {0.f, 0.f, 0.f, 0.f};
        c = MFMA16(a0, bf[nsub][0], c);
        c = MFMA16(a1, bf[nsub][1], c);
        colacc[nsub] += __expf(c[0]) + __expf(c[1]) + __expf(c[2]) + __expf(c[3]);
      }
    }
  }
  #pragma unroll
  for (int nsub = 0; nsub < 4; nsub++) {
    colacc[nsub] += __shfl_xor(colacc[nsub], 16, 64);
    colacc[nsub] += __shfl_xor(colacc[nsub], 32, 64);
  }
  float v = colacc[0];
  v = (quad == 1) ? colacc[1] : v;
  v = (quad == 2) ? colacc[2] : v;
  v = (quad == 3) ? colacc[3] : v;
  inv_colsum[bh * NN + n0 + quad * 16 + col] = 1.0f / v;
}

// ---------------------------------------------------------------------------
// Pass 2 (new): all tiles staged bf16 via global_load_lds with SOURCE-side
// XOR swizzle (LDS stays linear [row][64], row's 16B-blocks permuted by
// block^(row&7)); every b128 read is bank-packed. Double-buffered, one
// barrier per n-tile. XCD-bijective swizzle groups same-bh k-tiles on one
// XCD for L2 sharing of the xk/xv streams.
// ---------------------------------------------------------------------------
#define NT 64
#define PW 72

__global__ __launch_bounds__(256) void hop_pass2(
    const float* __restrict__ Km, const float* __restrict__ Vm,
    const bf16_t* __restrict__ xk16, const bf16_t* __restrict__ xkT16,
    const bf16_t* __restrict__ xvT16,
    const float* __restrict__ inv_colsum, float* __restrict__ out)
{
  __shared__ __align__(16) bf16_t xks[2][NT * DD];  // [n][d] (blocks swizzled)
  __shared__ __align__(16) bf16_t xkT[2][DD * NT];  // [d][n]
  __shared__ __align__(16) bf16_t xvT[2][DD * NT];
  __shared__ __align__(16) bf16_t wt[4][16 * PW];   // per-wave w [k][n]

  const int tid  = threadIdx.x;
  const int wave = tid >> 6, lane = tid & 63;
  const int col  = lane & 15, quad = lane >> 4;
  const int bid  = blockIdx.x;
  const int bh   = (bid & 7) + 8 * ((bid >> 3) & 7);  // same-bh ktiles -> same XCD
  const int k0   = (bid >> 6) * 64 + wave * 16;

  const float*  Kb   = Km    + (size_t)bh * KP * DD;
  const float*  Vb   = Vm    + (size_t)bh * KP * DD;
  const bf16_t* xkb  = xk16  + (size_t)bh * NN * DD;
  const bf16_t* xkTb = xkT16 + (size_t)bh * DD * NN;
  const bf16_t* xvTb = xvT16 + (size_t)bh * DD * NN;
  const float*  inv  = inv_colsum + bh * NN;

  const bf16x8 ak0 = cvt8(Kb + (size_t)(k0 + col) * DD + quad * 8);
  const bf16x8 ak1 = cvt8(Kb + (size_t)(k0 + col) * DD + 32 + quad * 8);

  f32x4 accK[4], accV[4];
  #pragma unroll
  for (int i = 0; i < 4; i++) {
    accK[i] = (f32x4){0.f, 0.f, 0.f, 0.f};
    accV[i] = (f32x4){0.f, 0.f, 0.f, 0.f};
  }
  float rows_part = 0.f;

  // staging geometry: chunk (wave*2+c) covers rows wave*16 + c*8 + (lane>>3),
  // 16B-block (lane&7). Source block pre-XORed so reads can de-swizzle.
  const int srl = lane >> 3;                 // row & 7 (swizzle key)
  const int r0  = wave * 16 + srl;           // rows sourced by this lane
  const int r1  = r0 + 8;
  const int sb  = ((lane & 7) ^ srl) * 8;    // swizzled source block offset (elems)
  const int lb0 = (wave * 2 + 0) * 512;      // lds elem offset of 1KB chunk
  const int lb1 = (wave * 2 + 1) * 512;

  // prologue: stage tile 0 into buf 0
  stage16(&xks[0][lb0], xkb + (size_t)r0 * DD + sb);
  stage16(&xks[0][lb1], xkb + (size_t)r1 * DD + sb);
  stage16(&xkT[0][lb0], xkTb + (size_t)r0 * NN + sb);
  stage16(&xkT[0][lb1], xkTb + (size_t)r1 * NN + sb);
  stage16(&xvT[0][lb0], xvTb + (size_t)r0 * NN + sb);
  stage16(&xvT[0][lb1], xvTb + (size_t)r1 * NN + sb);
  __syncthreads();  // compiler drains vmcnt(0) before s_barrier

  int cur = 0;
  for (int n0 = 0; n0 < NN; n0 += NT) {
    // issue next tile's DMA into the other buffer (its readers drained at the
    // barrier that ended the previous iteration)
    if (n0 + NT < NN) {
      const int nx = n0 + NT;
      const int nb = cur ^ 1;
      stage16(&xks[nb][lb0], xkb + (size_t)(nx + r0) * DD + sb);
      stage16(&xks[nb][lb1], xkb + (size_t)(nx + r1) * DD + sb);
      stage16(&xkT[nb][lb0], xkTb + (size_t)r0 * NN + nx + sb);
      stage16(&xkT[nb][lb1], xkTb + (size_t)r1 * NN + nx + sb);
      stage16(&xvT[nb][lb0], xvTb + (size_t)r0 * NN + nx + sb);
      stage16(&xvT[nb][lb1], xvTb + (size_t)r1 * NN + nx + sb);
    }

    float ic[4];
    #pragma unroll
    for (int ns = 0; ns < 4; ns++) ic[ns] = inv[n0 + ns * 16 + col];

    const int key = col & 7;

    // S: 16k x 64n, B-frags de-swizzled b128 reads (bank-packed)
    f32x4 s[4];
    #pragma unroll
    for (int ns = 0; ns < 4; ns++) {
      const bf16_t* bp = &xks[cur][(ns * 16 + col) * DD];
      const bf16x8 b0 = *(const bf16x8*)(bp + 8 * (quad ^ key));
      const bf16x8 b1 = *(const bf16x8*)(bp + 8 * ((quad + 4) ^ key));
      f32x4 c = {0.f, 0.f, 0.f, 0.f};
      c = MFMA16(ak0, b0, c);
      c = MFMA16(ak1, b1, c);
      s[ns] = c;
    }
    // w = exp(S)*inv_colsum -> per-wave tile
    bf16_t* wr = wt[wave];
    #pragma unroll
    for (int ns = 0; ns < 4; ns++) {
      #pragma unroll
      for (int r = 0; r < 4; r++)
        wr[(quad * 4 + r) * PW + ns * 16 + col] = (bf16_t)(__expf(s[ns][r]) * ic[ns]);
    }
    // same-wave LDS write->read: lgkmcnt ordering suffices
    const bf16x8 wa0 = *(const bf16x8*)(wr + col * PW + quad * 8);
    const bf16x8 wa1 = *(const bf16x8*)(wr + col * PW + 32 + quad * 8);
    #pragma unroll
    for (int j = 0; j < 8; j++) rows_part += (float)wa0[j] + (float)wa1[j];

    // PV: acc[k][d] += w . x, B-frags de-swizzled b128 reads
    #pragma unroll
    for (int dt = 0; dt < 4; dt++) {
      const int d = dt * 16 + col;
      const bf16_t* kp = &xkT[cur][d * NT];
      const bf16_t* vp = &xvT[cur][d * NT];
      const bf16x8 bk0 = *(const bf16x8*)(kp + 8 * (quad ^ key));
      const bf16x8 bk1 = *(const bf16x8*)(kp + 8 * ((quad + 4) ^ key));
      const bf16x8 bv0 = *(const bf16x8*)(vp + 8 * (quad ^ key));
      const bf16x8 bv1 = *(const bf16x8*)(vp + 8 * ((quad + 4) ^ key));
      accK[dt] = MFMA16(wa0, bk0, accK[dt]);
      accK[dt] = MFMA16(wa1, bk1, accK[dt]);
      accV[dt] = MFMA16(wa0, bv0, accV[dt]);
      accV[dt] = MFMA16(wa1, bv1, accV[dt]);
    }

    __syncthreads();  // drains vmcnt(0) (next tile staged) + lgkmcnt (reads done)
    cur ^= 1;
  }

  float rs = rows_part;
  rs += __shfl_xor(rs, 16, 64);
  rs += __shfl_xor(rs, 32, 64);
  float invrs[4];
  #pragma unroll
  for (int r = 0; r < 4; r++) invrs[r] = 1.0f / __shfl(rs, quad * 4 + r, 64);

  const size_t base = (size_t)bh * KP * DD;
  #pragma unroll
  for (int dt = 0; dt < 4; dt++) {
    #pragma unroll
    for (int r = 0; r < 4; r++) {
      const int k = k0 + quad * 4 + r;
      const int d = dt * 16 + col;
      const size_t idx = base + (size_t)k * DD + d;
      out[idx]       = accK[dt][r] * invrs[r] - Kb[(size_t)k * DD + d];
      out[GSZ + idx] = accV[dt][r] * invrs[r] - Vb[(size_t)k * DD + d];
    }
  }
}

// ---------------------------------------------------------------------------
// Fallback path (ws too small for bf16 scratch): previous verified kernels.
// ---------------------------------------------------------------------------
__global__ __launch_bounds__(256) void hop_pass1_fb(
    const float* __restrict__ Km, const float* __restrict__ xk,
    float* __restrict__ inv_colsum)
{
  __shared__ __align__(16) bf16_t Ks[128 * 72];
  const int tid  = threadIdx.x;
  const int wave = tid >> 6, lane = tid & 63;
  const int col  = lane & 15, quad = lane >> 4;
  const int bh = blockIdx.y;
  const int n0 = blockIdx.x * 256 + wave * 64;
  const float* Kb  = Km + (size_t)bh * KP * DD;
  const float* xkb = xk + (size_t)bh * NN * DD;
  bf16x8 bf[4][2];
  #pragma unroll
  for (int nsub = 0; nsub < 4; nsub++) {
    const float* p = xkb + (size_t)(n0 + nsub * 16 + col) * DD + quad * 8;
    bf[nsub][0] = cvt8(p);
    bf[nsub][1] = cvt8(p + 32);
  }
  float colacc[4] = {0.f, 0.f, 0.f, 0.f};
  const int srow = tid >> 1, sdo = (tid & 1) * 32;
  for (int kc = 0; kc < KP; kc += 128) {
    __syncthreads();
    const float* src = Kb + (size_t)(kc + srow) * DD + sdo;
    #pragma unroll
    for (int u = 0; u < 4; u++) {
      const f32x4 p0 = *(const f32x4*)(src + 8 * u);
      const f32x4 p1 = *(const f32x4*)(src + 8 * u + 4);
      *(bf16x8*)(Ks + srow * 72 + sdo + 8 * u) = cvt8v(p0, p1);
    }
    __syncthreads();
    #pragma unroll
    for (int ks = 0; ks < 8; ks++) {
      const bf16x8 a0 = *(const bf16x8*)(Ks + (ks * 16 + col) * 72 + quad * 8);
      const bf16x8 a1 = *(const bf16x8*)(Ks + (ks * 16 + col) * 72 + 32 + quad * 8);
      #pragma unroll
      for (int nsub = 0; nsub < 4; nsub++) {
        f32x4 c = {0.f, 0.f, 0.f, 0.f};
        c = MFMA16(a0, bf[nsub][0], c);
        c = MFMA16(a1, bf[nsub][1], c);
        colacc[nsub] += __expf(c[0]) + __expf(c[1]) + __expf(c[2]) + __expf(c[3]);
      }
    }
  }
  #pragma unroll
  for (int nsub = 0; nsub < 4; nsub++) {
    colacc[nsub] += __shfl_xor(colacc[nsub], 16, 64);
    colacc[nsub] += __shfl_xor(colacc[nsub], 32, 64);
  }
  float v = colacc[0];
  v = (quad == 1) ? colacc[1] : v;
  v = (quad == 2) ? colacc[2] : v;
  v = (quad == 3) ? colacc[3] : v;
  inv_colsum[bh * NN + n0 + quad * 16 + col] = 1.0f / v;
}

__global__ __launch_bounds__(256) void hop_pass2_fb(
    const float* __restrict__ Km, const float* __restrict__ Vm,
    const float* __restrict__ xk, const float* __restrict__ xv,
    const float* __restrict__ inv_colsum, float* __restrict__ out)
{
  __shared__ __align__(16) bf16_t xksf[NT * PW];
  __shared__ __align__(16) bf16_t xkTf[DD * NT];
  __shared__ __align__(16) bf16_t xvTf[DD * NT];
  __shared__ __align__(16) bf16_t wtf[4][16 * PW];

  const int tid  = threadIdx.x;
  const int wave = tid >> 6, lane = tid & 63;
  const int col  = lane & 15, quad = lane >> 4;
  const int bh   = blockIdx.x >> 3;
  const int k0   = (blockIdx.x & 7) * 64 + wave * 16;

  const float* Kb  = Km + (size_t)bh * KP * DD;
  const float* Vb  = Vm + (size_t)bh * KP * DD;
  const float* xkb = xk + (size_t)bh * NN * DD;
  const float* xvb = xv + (size_t)bh * NN * DD;
  const float* inv = inv_colsum + bh * NN;

  const bf16x8 ak0 = cvt8(Kb + (size_t)(k0 + col) * DD + quad * 8);
  const bf16x8 ak1 = cvt8(Kb + (size_t)(k0 + col) * DD + 32 + quad * 8);

  f32x4 accK[4], accV[4];
  #pragma unroll
  for (int i = 0; i < 4; i++) {
    accK[i] = (f32x4){0.f, 0.f, 0.f, 0.f};
    accV[i] = (f32x4){0.f, 0.f, 0.f, 0.f};
  }
  float rows_part = 0.f;

  const int sn = tid >> 2;
  const int sd = (tid & 3) * 16;
  const int shi = sn >> 3, slo = sn & 7;

  for (int n0 = 0; n0 < NN; n0 += NT) {
    f32x4 gk[4], gv[4];
    #pragma unroll
    for (int u = 0; u < 4; u++) {
      gk[u] = *(const f32x4*)(xkb + (size_t)(n0 + sn) * DD + sd + 4 * u);
      gv[u] = *(const f32x4*)(xvb + (size_t)(n0 + sn) * DD + sd + 4 * u);
    }
    float ic[4];
    #pragma unroll
    for (int nsub = 0; nsub < 4; nsub++) ic[nsub] = inv[n0 + nsub * 16 + col];

    __syncthreads();
    *(bf16x8*)(xksf + sn * PW + sd)     = cvt8v(gk[0], gk[1]);
    *(bf16x8*)(xksf + sn * PW + sd + 8) = cvt8v(gk[2], gk[3]);
    #pragma unroll
    for (int j = 0; j < 16; j++) {
      const int d   = sd + j;
      const int off = d * NT + (((shi) ^ (d >> 3)) << 3) + slo;
      xkTf[off] = (bf16_t)gk[j >> 2][j & 3];
      xvTf[off] = (bf16_t)gv[j >> 2][j & 3];
    }
    __syncthreads();

    f32x4 s[4];
    #pragma unroll
    for (int nsub = 0; nsub < 4; nsub++) {
      const bf16x8 b0 = *(const bf16x8*)(xksf + (nsub * 16 + col) * PW + quad * 8);
      const bf16x8 b1 = *(const bf16x8*)(xksf + (nsub * 16 + col) * PW + 32 + quad * 8);
      f32x4 c = {0.f, 0.f, 0.f, 0.f};
      c = MFMA16(ak0, b0, c);
      c = MFMA16(ak1, b1, c);
      s[nsub] = c;
    }
    bf16_t* wr = wtf[wave];
    #pragma unroll
    for (int nsub = 0; nsub < 4; nsub++) {
      #pragma unroll
      for (int r = 0; r < 4; r++)
        wr[(quad * 4 + r) * PW + nsub * 16 + col] = (bf16_t)(__expf(s[nsub][r]) * ic[nsub]);
    }
    const bf16x8 wa0 = *(const bf16x8*)(wr + col * PW + quad * 8);
    const bf16x8 wa1 = *(const bf16x8*)(wr + col * PW + 32 + quad * 8);
    #pragma unroll
    for (int j = 0; j < 8; j++) rows_part += (float)wa0[j] + (float)wa1[j];

    #pragma unroll
    for (int dt = 0; dt < 4; dt++) {
      const int d = dt * 16 + col, dhi = d >> 3;
      const bf16x8 bk0 = *(const bf16x8*)(xkTf + d * NT + ((quad ^ dhi) << 3));
      const bf16x8 bk1 = *(const bf16x8*)(xkTf + d * NT + (((4 + quad) ^ dhi) << 3));
      const bf16x8 bv0 = *(const bf16x8*)(xvTf + d * NT + ((quad ^ dhi) << 3));
      const bf16x8 bv1 = *(const bf16x8*)(xvTf + d * NT + (((4 + quad) ^ dhi) << 3));
      accK[dt] = MFMA16(wa0, bk0, accK[dt]);
      accK[dt] = MFMA16(wa1, bk1, accK[dt]);
      accV[dt] = MFMA16(wa0, bv0, accV[dt]);
      accV[dt] = MFMA16(wa1, bv1, accV[dt]);
    }
  }

  float rs = rows_part;
  rs += __shfl_xor(rs, 16, 64);
  rs += __shfl_xor(rs, 32, 64);
  float invrs[4];
  #pragma unroll
  for (int r = 0; r < 4; r++) invrs[r] = 1.0f / __shfl(rs, quad * 4 + r, 64);

  const size_t base = (size_t)bh * KP * DD;
  #pragma unroll
  for (int dt = 0; dt < 4; dt++) {
    #pragma unroll
    for (int r = 0; r < 4; r++) {
      const int k = k0 + quad * 4 + r;
      const int d = dt * 16 + col;
      const size_t idx = base + (size_t)k * DD + d;
      out[idx]       = accK[dt][r] * invrs[r] - Kb[(size_t)k * DD + d];
      out[GSZ + idx] = accV[dt][r] * invrs[r] - Vb[(size_t)k * DD + d];
    }
  }
}

extern "C" void kernel_launch(void* const* d_in, const int* in_sizes, int n_in,
                              void* d_out, int out_size, void* d_ws, size_t ws_size,
                              hipStream_t stream)
{
  (void)in_sizes; (void)n_in; (void)out_size;
  const float* Km = (const float*)d_in[0];
  const float* Vm = (const float*)d_in[1];
  const float* xk = (const float*)d_in[2];
  const float* xv = (const float*)d_in[3];
  float* out = (float*)d_out;
  float* inv_colsum = (float*)d_ws;  // BH*NN floats = 1 MB

  const size_t SCRE = (size_t)BH * NN * DD;  // elems per bf16 scratch array
  const size_t NEED = (size_t)BH * NN * sizeof(float) + 3 * SCRE * sizeof(bf16_t);

  if (ws_size >= NEED) {
    bf16_t* xk16  = (bf16_t*)((char*)d_ws + (size_t)BH * NN * sizeof(float));
    bf16_t* xkT16 = xk16 + SCRE;
    bf16_t* xvT16 = xkT16 + SCRE;
    hop_prep<<<dim3(NN / 64, BH), 256, 0, stream>>>(xk, xv, xk16, xkT16, xvT16);
    hop_pass1<<<dim3((NN / 256) * BH), 256, 0, stream>>>(Km, xk16, inv_colsum);
    hop_pass2<<<dim3(BH * (KP / 64)), 256, 0, stream>>>(Km, Vm, xk16, xkT16, xvT16,
                                                        inv_colsum, out);
  } else {
    hop_pass1_fb<<<dim3(NN / 256, BH), 256, 0, stream>>>(Km, xk, inv_colsum);
    hop_pass2_fb<<<dim3(BH * (KP / 64)), 256, 0, stream>>>(Km, Vm, xk, xv,
                                                           inv_colsum, out);
  }
}